// Round 16
// baseline (194.358 us; speedup 1.0000x reference)
//
#include <hip/hip_runtime.h>
#include <hip/hip_bf16.h>

// CharLSTM: B=128, TW=256, TC=25, V=128, D=32, H=64 (4H=256), N=32768 seqs.
//
// R16 = R15 (71.1 us) with __launch_bounds__(256, 6) — single-variable
// occupancy experiment:
//  R15 model closure: wall 853 cyc/wave-ts, VALU 563 (trans 224 + full-
//  rate 340), MFMA 130 -> combined issue 81%; occupancy measured 34.5%
//  (~11 waves/CU). Per-SIMD VGPR budget is floor-based (~8-reg granule):
//  total demand (arch 52 + AGPR ~25) sits near the 6-waves/SIMD cap
//  (512/6 ~ 85). Forcing min 6 waves/EU adds +50% resident TLP to fill
//  the 19% idle issue slots.
//  Tripwire: FETCH/WRITE balloon => allocator spilled => revert to R15.

#define SEQ_M 16
#define TC_LEN 25
#define H_N 64
#define D_N 32
#define G4_N 256
#define V_N 128

typedef __attribute__((ext_vector_type(8))) short bf16x8;
typedef __attribute__((ext_vector_type(4))) float f32x4;
typedef __attribute__((ext_vector_type(2))) float f32x2;
typedef __attribute__((ext_vector_type(4))) int i32x4;

#define SCALE_SIG (-1.4426950408889634f)   /* -log2(e)  */
#define SCALE_G   ( 2.8853900817779268f)   /* 2*log2(e) */

// LDS-only barrier: drain LDS ops (cross-wave h exchange) but let
// global (EW) loads stay outstanding across the barrier.
#define LBAR() asm volatile("s_waitcnt lgkmcnt(0)\n\ts_barrier" ::: "memory")

__device__ __forceinline__ ushort bf16_rne(float x) {
    const uint u = __float_as_uint(x);
    return (ushort)((u + 0x7fffu + ((u >> 16) & 1u)) >> 16);
}
__device__ __forceinline__ float bf16_tof(ushort h) {
    return __uint_as_float(((uint)h) << 16);
}
// swizzled byte offset into a [16][64] bf16 (2 KB) tile
__device__ __forceinline__ int hswz(int row, int kbyte) {
    const int b = row * 128 + kbyte;
    return b ^ ((row & 7) << 4);
}

// ---- prologue 1: EWr[v][c16][tile] = ((E.W)[v][tile*64+c16]+b)*gate_scale ----
__global__ void ew_precompute(const float* __restrict__ E,
                              const float* __restrict__ W,
                              const float* __restrict__ b,
                              float* __restrict__ EWr) {
    const int v = blockIdx.x;
    const int j = threadIdx.x;           // output col = (j>>6)*64 + (j&63)
    float acc = b[j];
#pragma unroll
    for (int d = 0; d < D_N; ++d)
        acc = fmaf(E[v * D_N + d], W[d * G4_N + j], acc);
    const int tile = j >> 6, c16 = j & 63;
    const float scale = (tile == 2) ? SCALE_G : SCALE_SIG;
    EWr[v * G4_N + c16 * 4 + tile] = acc * scale;
}

// ---- prologue 2: Upk[col][k] bf16-hi, pre-scaled ----
__global__ void u_pack(const float* __restrict__ U, ushort* __restrict__ Upk) {
    const int k   = blockIdx.x;          // 0..63
    const int col = threadIdx.x;         // 0..255
    const float scale = ((col >> 6) == 2) ? SCALE_G : SCALE_SIG;
    const float uv = U[k * G4_N + col] * scale;
    Upk[col * 64 + k] = bf16_rne(uv);
}

__global__ __launch_bounds__(256, 6) void char_lstm_mfma(
    const int* __restrict__ chars,    // [N][25]
    const ushort* __restrict__ Upk,   // [256][64] bf16-hi frag table
    const float* __restrict__ EWr,    // [128][64][4] permuted+scaled
    float* __restrict__ out)          // [N][64]
{
    const int j = threadIdx.x;
    const int w = j >> 6;            // wave 0..3
    const int l = j & 63;            // lane
    const int q = l >> 4;            // lane group 0..3
    const int n16 = l & 15;          // 0..15
    const int c16 = w * 16 + n16;    // this thread's unit/col-in-gate
    const int seq0 = blockIdx.x * SEQ_M;

    __shared__ int ibuf[TC_LEN][SEQ_M];              // byte offsets
    __shared__ ushort hbuf[2][SEQ_M * H_N];          // [buf], bf16-RNE h, 4 KB

    // stage chars transposed as EWr BYTE offsets (row stride 256*4 = 1024)
    for (int idx = j; idx < TC_LEN * SEQ_M; idx += 256) {
        const int s = idx & 15, tt = idx >> 4;
        ibuf[tt][s] = chars[(seq0 + s) * TC_LEN + tt] << 10;
    }

    // ---- load pre-packed U-hi fragments: 8x dwordx4, L2-hot ----
    bf16x8 bh[4][2];
#pragma unroll
    for (int tile = 0; tile < 4; ++tile) {
        const ushort* ub = Upk + (tile * 64 + c16) * 64 + 8 * q;
#pragma unroll
        for (int ks = 0; ks < 2; ++ks)
            bh[tile][ks] = *(const bf16x8*)(ub + ks * 32);
    }

    __syncthreads();   // ibuf visible (full barrier once, prologue only)

    // hoisted LDS offsets + uniform EW base with 32-bit per-lane offsets
    const int offA0 = hswz(n16, 16 * q);
    const int offA1 = hswz(n16, 64 + 16 * q);
    int offW[4];
#pragma unroll
    for (int r = 0; r < 4; ++r) offW[r] = hswz(4 * q + r, c16 * 2);
    const char* ewbase = (const char*)EWr;     // uniform -> SGPR pair
    const uint  c16b   = (uint)(c16 * 16);     // per-lane 32-bit bias

    f32x2 cP[2] = {{0.0f, 0.0f}, {0.0f, 0.0f}};
    f32x4 ewvA[4], ewvB[4];
    f32x4 acc[4];
    const f32x4 zero4 = {0.0f, 0.0f, 0.0f, 0.0f};

    // activation: z = (ADD_EW ? acc+ew : ew), packed f32x2 over r-pairs
#define ACT_BODY(HN, EWV, ADD_EW, WRITE_OUT)                                  \
    {                                                                         \
        _Pragma("unroll")                                                     \
        for (int p = 0; p < 2; ++p) {                                         \
            const int r0 = 2 * p, r1 = 2 * p + 1;                             \
            f32x2 z0, z1, z2, z3;                                             \
            if (ADD_EW) {                                                     \
                z0[0] = acc[0][r0] + EWV[r0][0]; z0[1] = acc[0][r1] + EWV[r1][0]; \
                z1[0] = acc[1][r0] + EWV[r0][1]; z1[1] = acc[1][r1] + EWV[r1][1]; \
                z2[0] = acc[2][r0] + EWV[r0][2]; z2[1] = acc[2][r1] + EWV[r1][2]; \
                z3[0] = acc[3][r0] + EWV[r0][3]; z3[1] = acc[3][r1] + EWV[r1][3]; \
            } else {                                                          \
                z0[0] = EWV[r0][0]; z0[1] = EWV[r1][0];                       \
                z1[0] = EWV[r0][1]; z1[1] = EWV[r1][1];                       \
                z2[0] = EWV[r0][2]; z2[1] = EWV[r1][2];                       \
                z3[0] = EWV[r0][3]; z3[1] = EWV[r1][3];                       \
            }                                                                 \
            f32x2 A, B, C, D;                                                 \
            A[0] = __builtin_amdgcn_exp2f(z0[0]); A[1] = __builtin_amdgcn_exp2f(z0[1]); \
            B[0] = __builtin_amdgcn_exp2f(z1[0]); B[1] = __builtin_amdgcn_exp2f(z1[1]); \
            C[0] = __builtin_amdgcn_exp2f(z2[0]); C[1] = __builtin_amdgcn_exp2f(z2[1]); \
            D[0] = __builtin_amdgcn_exp2f(z3[0]); D[1] = __builtin_amdgcn_exp2f(z3[1]); \
            const f32x2 di = A + 1.0f, df = B + 1.0f, dg = C + 1.0f;          \
            const f32x2 m1 = di * dg;                                         \
            const f32x2 num = cP[p] * m1 + (C - 1.0f) * df;                   \
            const f32x2 qa = m1 * df;                                         \
            f32x2 Q;                                                          \
            Q[0] = __builtin_amdgcn_rcpf(qa[0]);                              \
            Q[1] = __builtin_amdgcn_rcpf(qa[1]);                              \
            cP[p] = num * Q;                                                  \
            const f32x2 cs = cP[p] * SCALE_G;                                 \
            f32x2 E2;                                                         \
            E2[0] = __builtin_amdgcn_exp2f(cs[0]);                            \
            E2[1] = __builtin_amdgcn_exp2f(cs[1]);                            \
            const f32x2 nh = E2 - 1.0f;                                       \
            const f32x2 Ph = (D + 1.0f) * (E2 + 1.0f);                        \
            f32x2 R;                                                          \
            R[0] = __builtin_amdgcn_rcpf(Ph[0]);                              \
            R[1] = __builtin_amdgcn_rcpf(Ph[1]);                              \
            const f32x2 h = nh * R;                                           \
            _Pragma("unroll")                                                 \
            for (int e = 0; e < 2; ++e) {                                     \
                const int r = 2 * p + e;                                      \
                if (WRITE_OUT) {                                              \
                    out[(seq0 + 4 * q + r) * H_N + c16] = h[e];               \
                } else {                                                      \
                    *(ushort*)((HN) + offW[r]) = bf16_rne(h[e]);              \
                }                                                             \
            }                                                                 \
        }                                                                     \
    }

#define PREFETCH_EW(EWV, T1)                                                  \
    {                                                                         \
        const i32x4 cv = *(const i32x4*)&ibuf[(T1)][4 * q];                   \
        _Pragma("unroll")                                                     \
        for (int r = 0; r < 4; ++r)                                           \
            EWV[r] = *(const f32x4*)(ewbase + (uint)(cv[r]) + c16b);          \
    }

    // single-term: 8 MFMA, 2-deep chains, zero-C first op
#define MFMA_CLUSTER(RB)                                                      \
    {                                                                         \
        const bf16x8 ah0 = *(const bf16x8*)((RB) + offA0);                    \
        const bf16x8 ah1 = *(const bf16x8*)((RB) + offA1);                    \
        __builtin_amdgcn_s_setprio(1);                                        \
        _Pragma("unroll")                                                     \
        for (int tile = 0; tile < 4; ++tile)                                  \
            acc[tile] = __builtin_amdgcn_mfma_f32_16x16x32_bf16(              \
                ah0, bh[tile][0], zero4, 0, 0, 0);                            \
        _Pragma("unroll")                                                     \
        for (int tile = 0; tile < 4; ++tile)                                  \
            acc[tile] = __builtin_amdgcn_mfma_f32_16x16x32_bf16(              \
                ah1, bh[tile][1], acc[tile], 0, 0, 0);                        \
        __builtin_amdgcn_s_setprio(0);                                        \
    }

    char* b0 = (char*)&hbuf[0][0];
    char* b1 = (char*)&hbuf[1][0];

    // ---- t = 0 (peeled): z = x-proj only (ewvA), h0 -> buf0 ----
    PREFETCH_EW(ewvA, 0);
    ACT_BODY(b0, ewvA, 0, 0);
    PREFETCH_EW(ewvB, 1);
    LBAR();

    // ---- t = 1..22 as 11 static-parity pairs ----
    // odd t consumes ewvB, even t consumes ewvA; prefetch fills the other.
    for (int tp = 0; tp < 11; ++tp) {
        // odd t: read buf0, write buf1
        MFMA_CLUSTER(b0);
        PREFETCH_EW(ewvA, 2 * tp + 2);
        ACT_BODY(b1, ewvB, 1, 0);
        LBAR();
        // even t: read buf1, write buf0
        MFMA_CLUSTER(b1);
        PREFETCH_EW(ewvB, 2 * tp + 3);
        ACT_BODY(b0, ewvA, 1, 0);
        LBAR();
    }

    // ---- t = 23: read buf0, write buf1 ----
    MFMA_CLUSTER(b0);
    PREFETCH_EW(ewvA, 24);
    ACT_BODY(b1, ewvB, 1, 0);
    LBAR();

    // ---- t = 24 (peeled): read buf1, write h_last to GLOBAL ----
    MFMA_CLUSTER(b1);
    ACT_BODY(b1, ewvA, 1, 1);

#undef ACT_BODY
#undef PREFETCH_EW
#undef MFMA_CLUSTER
}

extern "C" void kernel_launch(void* const* d_in, const int* in_sizes, int n_in,
                              void* d_out, int out_size, void* d_ws, size_t ws_size,
                              hipStream_t stream) {
    const int*   chars = (const int*)d_in[0];
    const float* E     = (const float*)d_in[1];
    const float* W     = (const float*)d_in[2];
    const float* U     = (const float*)d_in[3];
    const float* b     = (const float*)d_in[4];
    float* out = (float*)d_out;
    float*  EWr = (float*)d_ws;                         // 131072 B
    ushort* Upk = (ushort*)((char*)d_ws + 131072);      // 32768 B

    const int N = in_sizes[0] / TC_LEN;             // 32768
    const int blocks = N / SEQ_M;                   // 2048

    ew_precompute<<<V_N, G4_N, 0, stream>>>(E, W, b, EWr);
    u_pack<<<H_N, G4_N, 0, stream>>>(U, Upk);
    char_lstm_mfma<<<blocks, 256, 0, stream>>>(chars, Upk, EWr, out);
}

// Round 17
// 69.813 us; speedup vs baseline: 2.7840x; 2.7840x over previous
//
#include <hip/hip_runtime.h>
#include <hip/hip_bf16.h>

// CharLSTM: B=128, TW=256, TC=25, V=128, D=32, H=64 (4H=256), N=32768 seqs.
//
// R17 = R15 (71.1 us, best) + v_cvt_pk_bf16_f32 h-packing:
//  R16's (256,6) experiment spilled catastrophically (FETCH 2.3MB->257MB)
//  -> occupancy axis is closed; reverted to R15's (256,4).
//  The h->bf16 store path used manual RNE bit-twiddling (~4 VALU/cell,
//  16/thread-ts). gfx950's v_cvt_pk_bf16_f32 (RNE) converts 2 f32 in one
//  instr: 1 cvt + 1 shift per cell-pair = saves ~12 instr/thread-ts.
//  Rounding identical -> bit-identical output vs R15.

#define SEQ_M 16
#define TC_LEN 25
#define H_N 64
#define D_N 32
#define G4_N 256
#define V_N 128

typedef __attribute__((ext_vector_type(8))) short bf16x8;
typedef __attribute__((ext_vector_type(4))) float f32x4;
typedef __attribute__((ext_vector_type(2))) float f32x2;
typedef __attribute__((ext_vector_type(4))) int i32x4;

#define SCALE_SIG (-1.4426950408889634f)   /* -log2(e)  */
#define SCALE_G   ( 2.8853900817779268f)   /* 2*log2(e) */

// LDS-only barrier: drain LDS ops (cross-wave h exchange) but let
// global (EW) loads stay outstanding across the barrier.
#define LBAR() asm volatile("s_waitcnt lgkmcnt(0)\n\ts_barrier" ::: "memory")

__device__ __forceinline__ ushort bf16_rne(float x) {
    const uint u = __float_as_uint(x);
    return (ushort)((u + 0x7fffu + ((u >> 16) & 1u)) >> 16);
}
__device__ __forceinline__ float bf16_tof(ushort h) {
    return __uint_as_float(((uint)h) << 16);
}
// swizzled byte offset into a [16][64] bf16 (2 KB) tile
__device__ __forceinline__ int hswz(int row, int kbyte) {
    const int b = row * 128 + kbyte;
    return b ^ ((row & 7) << 4);
}

// ---- prologue 1: EWr[v][c16][tile] = ((E.W)[v][tile*64+c16]+b)*gate_scale ----
__global__ void ew_precompute(const float* __restrict__ E,
                              const float* __restrict__ W,
                              const float* __restrict__ b,
                              float* __restrict__ EWr) {
    const int v = blockIdx.x;
    const int j = threadIdx.x;           // output col = (j>>6)*64 + (j&63)
    float acc = b[j];
#pragma unroll
    for (int d = 0; d < D_N; ++d)
        acc = fmaf(E[v * D_N + d], W[d * G4_N + j], acc);
    const int tile = j >> 6, c16 = j & 63;
    const float scale = (tile == 2) ? SCALE_G : SCALE_SIG;
    EWr[v * G4_N + c16 * 4 + tile] = acc * scale;
}

// ---- prologue 2: Upk[col][k] bf16-hi, pre-scaled ----
__global__ void u_pack(const float* __restrict__ U, ushort* __restrict__ Upk) {
    const int k   = blockIdx.x;          // 0..63
    const int col = threadIdx.x;         // 0..255
    const float scale = ((col >> 6) == 2) ? SCALE_G : SCALE_SIG;
    const float uv = U[k * G4_N + col] * scale;
    Upk[col * 64 + k] = bf16_rne(uv);
}

__global__ __launch_bounds__(256, 4) void char_lstm_mfma(
    const int* __restrict__ chars,    // [N][25]
    const ushort* __restrict__ Upk,   // [256][64] bf16-hi frag table
    const float* __restrict__ EWr,    // [128][64][4] permuted+scaled
    float* __restrict__ out)          // [N][64]
{
    const int j = threadIdx.x;
    const int w = j >> 6;            // wave 0..3
    const int l = j & 63;            // lane
    const int q = l >> 4;            // lane group 0..3
    const int n16 = l & 15;          // 0..15
    const int c16 = w * 16 + n16;    // this thread's unit/col-in-gate
    const int seq0 = blockIdx.x * SEQ_M;

    __shared__ int ibuf[TC_LEN][SEQ_M];              // byte offsets
    __shared__ ushort hbuf[2][SEQ_M * H_N];          // [buf], bf16-RNE h, 4 KB

    // stage chars transposed as EWr BYTE offsets (row stride 256*4 = 1024)
    for (int idx = j; idx < TC_LEN * SEQ_M; idx += 256) {
        const int s = idx & 15, tt = idx >> 4;
        ibuf[tt][s] = chars[(seq0 + s) * TC_LEN + tt] << 10;
    }

    // ---- load pre-packed U-hi fragments: 8x dwordx4, L2-hot ----
    bf16x8 bh[4][2];
#pragma unroll
    for (int tile = 0; tile < 4; ++tile) {
        const ushort* ub = Upk + (tile * 64 + c16) * 64 + 8 * q;
#pragma unroll
        for (int ks = 0; ks < 2; ++ks)
            bh[tile][ks] = *(const bf16x8*)(ub + ks * 32);
    }

    __syncthreads();   // ibuf visible (full barrier once, prologue only)

    // hoisted LDS offsets + uniform EW base with 32-bit per-lane offsets
    const int offA0 = hswz(n16, 16 * q);
    const int offA1 = hswz(n16, 64 + 16 * q);
    int offW[4];
#pragma unroll
    for (int r = 0; r < 4; ++r) offW[r] = hswz(4 * q + r, c16 * 2);
    const char* ewbase = (const char*)EWr;     // uniform -> SGPR pair
    const uint  c16b   = (uint)(c16 * 16);     // per-lane 32-bit bias

    f32x2 cP[2] = {{0.0f, 0.0f}, {0.0f, 0.0f}};
    f32x4 ewvA[4], ewvB[4];
    f32x4 acc[4];
    const f32x4 zero4 = {0.0f, 0.0f, 0.0f, 0.0f};

    // activation: z = (ADD_EW ? acc+ew : ew), packed f32x2 over r-pairs
#define ACT_BODY(HN, EWV, ADD_EW, WRITE_OUT)                                  \
    {                                                                         \
        _Pragma("unroll")                                                     \
        for (int p = 0; p < 2; ++p) {                                         \
            const int r0 = 2 * p, r1 = 2 * p + 1;                             \
            f32x2 z0, z1, z2, z3;                                             \
            if (ADD_EW) {                                                     \
                z0[0] = acc[0][r0] + EWV[r0][0]; z0[1] = acc[0][r1] + EWV[r1][0]; \
                z1[0] = acc[1][r0] + EWV[r0][1]; z1[1] = acc[1][r1] + EWV[r1][1]; \
                z2[0] = acc[2][r0] + EWV[r0][2]; z2[1] = acc[2][r1] + EWV[r1][2]; \
                z3[0] = acc[3][r0] + EWV[r0][3]; z3[1] = acc[3][r1] + EWV[r1][3]; \
            } else {                                                          \
                z0[0] = EWV[r0][0]; z0[1] = EWV[r1][0];                       \
                z1[0] = EWV[r0][1]; z1[1] = EWV[r1][1];                       \
                z2[0] = EWV[r0][2]; z2[1] = EWV[r1][2];                       \
                z3[0] = EWV[r0][3]; z3[1] = EWV[r1][3];                       \
            }                                                                 \
            f32x2 A, B, C, D;                                                 \
            A[0] = __builtin_amdgcn_exp2f(z0[0]); A[1] = __builtin_amdgcn_exp2f(z0[1]); \
            B[0] = __builtin_amdgcn_exp2f(z1[0]); B[1] = __builtin_amdgcn_exp2f(z1[1]); \
            C[0] = __builtin_amdgcn_exp2f(z2[0]); C[1] = __builtin_amdgcn_exp2f(z2[1]); \
            D[0] = __builtin_amdgcn_exp2f(z3[0]); D[1] = __builtin_amdgcn_exp2f(z3[1]); \
            const f32x2 di = A + 1.0f, df = B + 1.0f, dg = C + 1.0f;          \
            const f32x2 m1 = di * dg;                                         \
            const f32x2 num = cP[p] * m1 + (C - 1.0f) * df;                   \
            const f32x2 qa = m1 * df;                                         \
            f32x2 Q;                                                          \
            Q[0] = __builtin_amdgcn_rcpf(qa[0]);                              \
            Q[1] = __builtin_amdgcn_rcpf(qa[1]);                              \
            cP[p] = num * Q;                                                  \
            const f32x2 cs = cP[p] * SCALE_G;                                 \
            f32x2 E2;                                                         \
            E2[0] = __builtin_amdgcn_exp2f(cs[0]);                            \
            E2[1] = __builtin_amdgcn_exp2f(cs[1]);                            \
            const f32x2 nh = E2 - 1.0f;                                       \
            const f32x2 Ph = (D + 1.0f) * (E2 + 1.0f);                        \
            f32x2 R;                                                          \
            R[0] = __builtin_amdgcn_rcpf(Ph[0]);                              \
            R[1] = __builtin_amdgcn_rcpf(Ph[1]);                              \
            const f32x2 h = nh * R;                                           \
            if (WRITE_OUT) {                                                  \
                out[(seq0 + 4 * q + r0) * H_N + c16] = h[0];                  \
                out[(seq0 + 4 * q + r1) * H_N + c16] = h[1];                  \
            } else {                                                          \
                uint hp;                                                      \
                asm("v_cvt_pk_bf16_f32 %0, %1, %2"                            \
                    : "=v"(hp) : "v"(h[0]), "v"(h[1]));                       \
                *(ushort*)((HN) + offW[r0]) = (ushort)hp;                     \
                *(ushort*)((HN) + offW[r1]) = (ushort)(hp >> 16);             \
            }                                                                 \
        }                                                                     \
    }

#define PREFETCH_EW(EWV, T1)                                                  \
    {                                                                         \
        const i32x4 cv = *(const i32x4*)&ibuf[(T1)][4 * q];                   \
        _Pragma("unroll")                                                     \
        for (int r = 0; r < 4; ++r)                                           \
            EWV[r] = *(const f32x4*)(ewbase + (uint)(cv[r]) + c16b);          \
    }

    // single-term: 8 MFMA, 2-deep chains, zero-C first op
#define MFMA_CLUSTER(RB)                                                      \
    {                                                                         \
        const bf16x8 ah0 = *(const bf16x8*)((RB) + offA0);                    \
        const bf16x8 ah1 = *(const bf16x8*)((RB) + offA1);                    \
        __builtin_amdgcn_s_setprio(1);                                        \
        _Pragma("unroll")                                                     \
        for (int tile = 0; tile < 4; ++tile)                                  \
            acc[tile] = __builtin_amdgcn_mfma_f32_16x16x32_bf16(              \
                ah0, bh[tile][0], zero4, 0, 0, 0);                            \
        _Pragma("unroll")                                                     \
        for (int tile = 0; tile < 4; ++tile)                                  \
            acc[tile] = __builtin_amdgcn_mfma_f32_16x16x32_bf16(              \
                ah1, bh[tile][1], acc[tile], 0, 0, 0);                        \
        __builtin_amdgcn_s_setprio(0);                                        \
    }

    char* b0 = (char*)&hbuf[0][0];
    char* b1 = (char*)&hbuf[1][0];

    // ---- t = 0 (peeled): z = x-proj only (ewvA), h0 -> buf0 ----
    PREFETCH_EW(ewvA, 0);
    ACT_BODY(b0, ewvA, 0, 0);
    PREFETCH_EW(ewvB, 1);
    LBAR();

    // ---- t = 1..22 as 11 static-parity pairs ----
    // odd t consumes ewvB, even t consumes ewvA; prefetch fills the other.
    for (int tp = 0; tp < 11; ++tp) {
        // odd t: read buf0, write buf1
        MFMA_CLUSTER(b0);
        PREFETCH_EW(ewvA, 2 * tp + 2);
        ACT_BODY(b1, ewvB, 1, 0);
        LBAR();
        // even t: read buf1, write buf0
        MFMA_CLUSTER(b1);
        PREFETCH_EW(ewvB, 2 * tp + 3);
        ACT_BODY(b0, ewvA, 1, 0);
        LBAR();
    }

    // ---- t = 23: read buf0, write buf1 ----
    MFMA_CLUSTER(b0);
    PREFETCH_EW(ewvA, 24);
    ACT_BODY(b1, ewvB, 1, 0);
    LBAR();

    // ---- t = 24 (peeled): read buf1, write h_last to GLOBAL ----
    MFMA_CLUSTER(b1);
    ACT_BODY(b1, ewvA, 1, 1);

#undef ACT_BODY
#undef PREFETCH_EW
#undef MFMA_CLUSTER
}

extern "C" void kernel_launch(void* const* d_in, const int* in_sizes, int n_in,
                              void* d_out, int out_size, void* d_ws, size_t ws_size,
                              hipStream_t stream) {
    const int*   chars = (const int*)d_in[0];
    const float* E     = (const float*)d_in[1];
    const float* W     = (const float*)d_in[2];
    const float* U     = (const float*)d_in[3];
    const float* b     = (const float*)d_in[4];
    float* out = (float*)d_out;
    float*  EWr = (float*)d_ws;                         // 131072 B
    ushort* Upk = (ushort*)((char*)d_ws + 131072);      // 32768 B

    const int N = in_sizes[0] / TC_LEN;             // 32768
    const int blocks = N / SEQ_M;                   // 2048

    ew_precompute<<<V_N, G4_N, 0, stream>>>(E, W, b, EWr);
    u_pack<<<H_N, G4_N, 0, stream>>>(U, Upk);
    char_lstm_mfma<<<blocks, 256, 0, stream>>>(chars, Upk, EWr, out);
}